// Round 2
// baseline (949.835 us; speedup 1.0000x reference)
//
#include <hip/hip_runtime.h>

// ---------------- Kernel 0: segment offsets from sorted batch ----------------
__global__ void k_offsets(const int* __restrict__ batch, int* __restrict__ start,
                          int N, int B) {
    int i = blockIdx.x * blockDim.x + threadIdx.x;
    if (i >= N) return;
    int b = batch[i];
    if (i == 0) {
        for (int g = 0; g <= b; ++g) start[g] = 0;
    } else {
        int pb = batch[i - 1];
        for (int g = pb + 1; g <= b; ++g) start[g] = i;
    }
    if (i == N - 1) {
        for (int g = b + 1; g <= B; ++g) start[g] = N;
    }
}

// ---------------- Kernel A: pool (mean/max) -> q -> LN -> folded w_eff ----------------
// one block per graph, 256 threads.
// Pooling: wave w owns rows n = s+w, s+w+4, ...; lane l reads dims 4l..4l+3 as float4
// (16B/lane coalesced vs 4B/lane column loads). LDS combine gives thread d the full
// mean/max for dim d.
// w_eff is stored FOLDED: w_eff[g,h,j] = (sum_r Wk[h*32+r,j]*QL[h*32+r]) * scale * ln_kv_w[j]
// so k_attn can compute logits on RAW x:
//   logit = rstd*(dot(A,x) - mu*sum(A)) + const(g,h) + mask_bias
// and const(g,h) = sum_j we*lnb is softmax-invariant within a segment -> dropped.
__global__ __launch_bounds__(256) void k_pool_q(
    const float* __restrict__ h, const int* __restrict__ start,
    const float* __restrict__ Wq, const float* __restrict__ Wk,
    const float* __restrict__ ln_q_w, const float* __restrict__ ln_q_b,
    const float* __restrict__ ln_kv_w, const float* __restrict__ logit_scale,
    float* __restrict__ mean_raw, float* __restrict__ w_eff)
{
    const int g = blockIdx.x;
    const int tid = threadIdx.x;
    const int w = tid >> 6;
    const int l = tid & 63;
    const int d = tid;
    const int s = start[g], e = start[g + 1];

    // ---- vectorized pooling: wave-per-row, float4 per lane, 2-deep unroll ----
    float4 sm = make_float4(0.f, 0.f, 0.f, 0.f);
    float4 mx = make_float4(-INFINITY, -INFINITY, -INFINITY, -INFINITY);
    int n = s + w;
    for (; n + 4 < e; n += 8) {
        const float4 a = *(const float4*)(h + (size_t)n * 256 + l * 4);
        const float4 b = *(const float4*)(h + (size_t)(n + 4) * 256 + l * 4);
        sm.x += a.x + b.x; sm.y += a.y + b.y; sm.z += a.z + b.z; sm.w += a.w + b.w;
        mx.x = fmaxf(mx.x, fmaxf(a.x, b.x)); mx.y = fmaxf(mx.y, fmaxf(a.y, b.y));
        mx.z = fmaxf(mx.z, fmaxf(a.z, b.z)); mx.w = fmaxf(mx.w, fmaxf(a.w, b.w));
    }
    if (n < e) {
        const float4 a = *(const float4*)(h + (size_t)n * 256 + l * 4);
        sm.x += a.x; sm.y += a.y; sm.z += a.z; sm.w += a.w;
        mx.x = fmaxf(mx.x, a.x); mx.y = fmaxf(mx.y, a.y);
        mx.z = fmaxf(mx.z, a.z); mx.w = fmaxf(mx.w, a.w);
    }

    __shared__ __align__(16) float PS[4][256];
    __shared__ __align__(16) float PM[4][256];
    *(float4*)(&PS[w][l * 4]) = sm;
    *(float4*)(&PM[w][l * 4]) = mx;
    __syncthreads();
    const float sum = (PS[0][d] + PS[1][d]) + (PS[2][d] + PS[3][d]);
    const float mxv = fmaxf(fmaxf(PM[0][d], PM[1][d]), fmaxf(PM[2][d], PM[3][d]));
    const float mean = sum / (float)(e - s);
    mean_raw[(size_t)g * 256 + d] = mean;

    __shared__ __align__(16) float X[512];   // [mean | max]
    __shared__ float QL[256];
    __shared__ float rs[4], rq[4];
    X[d] = mean;
    X[256 + d] = mxv;
    __syncthreads();

    // q[d] = sum_j X[j] * Wq[d,j]   (Wq is (256,512) row-major)
    float q = 0.f;
    const float* wqr = Wq + (size_t)d * 512;
    #pragma unroll 8
    for (int j = 0; j < 512; j += 4) {
        float4 w4 = *(const float4*)(wqr + j);
        q += w4.x * X[j] + w4.y * X[j + 1] + w4.z * X[j + 2] + w4.w * X[j + 3];
    }
    // block LayerNorm over the 256 q values
    float s1 = q, s2 = q * q;
    #pragma unroll
    for (int off = 1; off < 64; off <<= 1) {
        s1 += __shfl_xor(s1, off);
        s2 += __shfl_xor(s2, off);
    }
    if ((d & 63) == 0) { rs[d >> 6] = s1; rq[d >> 6] = s2; }
    __syncthreads();
    const float t1 = rs[0] + rs[1] + rs[2] + rs[3];
    const float t2 = rq[0] + rq[1] + rq[2] + rq[3];
    const float mu = t1 * (1.f / 256.f);
    const float var = t2 * (1.f / 256.f) - mu * mu;
    const float rstd = rsqrtf(var + 1e-5f);
    QL[d] = (q - mu) * rstd * ln_q_w[d] + ln_q_b[d];
    __syncthreads();

    // folded A[h, j=d] = (sum_{d2 in head h} Wk[d2, d] * QL[d2]) * scale * ln_kv_w[d]
    const float scale = logit_scale[0] * 0.17677669529663687f; // 1/sqrt(32)
    const float fold = scale * ln_kv_w[d];
    #pragma unroll
    for (int hh = 0; hh < 8; ++hh) {
        float a = 0.f;
        #pragma unroll 8
        for (int r = 0; r < 32; ++r) {
            a += Wk[(size_t)(hh * 32 + r) * 256 + d] * QL[hh * 32 + r];
        }
        w_eff[((size_t)g * 8 + hh) * 256 + d] = a * fold;
    }
}

// ---------------- Kernel B: logits on raw x + online segment softmax + u ----------------
// one block per graph, 4 waves; wave w handles nodes s+w, s+w+4, ...
// lane layout: hh = l>>3 (head), p = l&7 (32-wide j-chunk)
// Per node: write RAW x to LDS, read chunk, compute {s1,s2,dotA} locally, ONE 3-level
// xor(1,2,4) reduce gives full LN stats AND the per-head dot. u accumulates raw x with
// weight e*rstd; the lnw/lnb correction is applied once in the epilogue:
//   sum_n e_n * h_ln[n,j] = lnw_j*(U[j] - Sw) + lnb_j*Z,  Sw = sum e*rstd*mu, Z = sum e
__global__ __launch_bounds__(256, 4) void k_attn(
    const float* __restrict__ h, const int* __restrict__ start,
    const int* __restrict__ cdr, const int* __restrict__ ifm,
    const float* __restrict__ ln_w, const float* __restrict__ ln_b,
    const float* __restrict__ w_eff,
    const float* __restrict__ cdr_bias, const float* __restrict__ iface_bias,
    float* __restrict__ u_norm)
{
    const int g = blockIdx.x;
    const int tid = threadIdx.x;
    const int w = tid >> 6;
    const int l = tid & 63;
    const int hh = l >> 3;
    const int p = l & 7;
    const int s = start[g], e = start[g + 1];
    const float cb = cdr_bias[0], ib = iface_bias[0];

    // folded key weights A for (head hh, chunk p)
    float we[32];
    {
        const float* wp = w_eff + ((size_t)g * 8 + hh) * 256 + p * 32;
        #pragma unroll
        for (int r = 0; r < 8; ++r) {
            float4 t = *(const float4*)(wp + r * 4);
            we[4 * r + 0] = t.x; we[4 * r + 1] = t.y; we[4 * r + 2] = t.z; we[4 * r + 3] = t.w;
        }
    }
    // s1h = sum_j A[hh][j]  (uniform across the 8 lanes of a head after reduce)
    float s1h = 0.f;
    #pragma unroll
    for (int r = 0; r < 32; ++r) s1h += we[r];
    s1h += __shfl_xor(s1h, 1);
    s1h += __shfl_xor(s1h, 2);
    s1h += __shfl_xor(s1h, 4);

    float m = -INFINITY, z = 0.f, sw = 0.f;
    float u[32];
    #pragma unroll
    for (int r = 0; r < 32; ++r) u[r] = 0.f;

    // padded row buffer: 32-float chunk c lives at float offset c*36
    __shared__ __align__(16) float hbuf[4][288];
    __shared__ __align__(16) float UF[4][8][264];   // padded: kills 16-way conflict on p*32 writes
    __shared__ float MW[4][8], ZW[4][8], SW[4][8], FG[4][8], IZ[8], SG[8];

    const int wofs = l * 4 + ((l >> 3) << 2); // padded offset of j = l*4
    const int rofs = p * 36;                  // padded base of chunk p

    int n = s + w;
    float4 xn = make_float4(0.f, 0.f, 0.f, 0.f);
    int cn = 0, im = 0;
    if (n < e) {                               // prefetch node 0
        xn = *(const float4*)(h + (size_t)n * 256 + l * 4);
        cn = cdr[n]; im = ifm[n];
    }
    while (n < e) {
        const float4 xc = xn;
        const int cc = cn, ic = im;
        const int n2 = n + 4;
        if (n2 < e) {                          // software-pipeline next node's x + masks
            xn = *(const float4*)(h + (size_t)n2 * 256 + l * 4);
            cn = cdr[n2]; im = ifm[n2];
        }

        *(float4*)(&hbuf[w][wofs]) = xc;       // RAW x (no LN yet)
        asm volatile("s_waitcnt lgkmcnt(0)" ::: "memory");

        float hv[32];
        #pragma unroll
        for (int r = 0; r < 8; ++r) {
            float4 t = *(const float4*)(&hbuf[w][rofs + r * 4]);
            hv[4 * r + 0] = t.x; hv[4 * r + 1] = t.y; hv[4 * r + 2] = t.z; hv[4 * r + 3] = t.w;
        }
        // local stats + dot over the chunk, then ONE shared 3-level reduce
        float s1 = 0.f, s2 = 0.f, dt = 0.f;
        #pragma unroll
        for (int r = 0; r < 32; ++r) {
            const float v = hv[r];
            s1 += v;
            s2 = fmaf(v, v, s2);
            dt = fmaf(v, we[r], dt);
        }
        #pragma unroll
        for (int off = 1; off < 8; off <<= 1) {
            s1 += __shfl_xor(s1, off);
            s2 += __shfl_xor(s2, off);
            dt += __shfl_xor(dt, off);
        }
        const float mu = s1 * (1.f / 256.f);
        const float var = s2 * (1.f / 256.f) - mu * mu;
        const float rstd = rsqrtf(var + 1e-5f);
        const float mb = cb * (float)cc + ib * (float)ic;
        const float lv = rstd * (dt - mu * s1h) + mb;

        const float nm = fmaxf(m, lv);
        const float ee = __expf(lv - nm);
        const float c = ee * rstd;
        if (__any(lv > m)) {                   // some head's max moved: rescale path
            const float a = __expf(m - nm);    // exp(-inf)=0 on first node
            z = z * a + ee;
            sw = sw * a + c * mu;
            #pragma unroll
            for (int r = 0; r < 32; ++r) u[r] = u[r] * a + c * hv[r];
            m = nm;
        } else {                               // common path: no rescale, 1 FMA per elem
            z += ee;
            sw += c * mu;
            #pragma unroll
            for (int r = 0; r < 32; ++r) u[r] = fmaf(c, hv[r], u[r]);
        }
        n = n2;
    }

    if (p == 0) { MW[w][hh] = m; ZW[w][hh] = z; SW[w][hh] = sw; }
    #pragma unroll
    for (int r = 0; r < 8; ++r) {
        float4 t = make_float4(u[4 * r], u[4 * r + 1], u[4 * r + 2], u[4 * r + 3]);
        *(float4*)(&UF[w][hh][p * 32 + r * 4]) = t;
    }
    __syncthreads();

    if (tid < 8) {
        const float mg = fmaxf(fmaxf(MW[0][tid], MW[1][tid]),
                               fmaxf(MW[2][tid], MW[3][tid]));
        float zg = 0.f, sg = 0.f;
        #pragma unroll
        for (int ww = 0; ww < 4; ++ww) {
            const float f = __expf(MW[ww][tid] - mg);  // empty wave: exp(-inf)=0
            FG[ww][tid] = f;
            zg += ZW[ww][tid] * f;
            sg += SW[ww][tid] * f;
        }
        IZ[tid] = 1.f / zg;
        SG[tid] = sg;
    }
    __syncthreads();

    const float lwj = ln_w[tid], lbj = ln_b[tid];
    #pragma unroll
    for (int h2 = 0; h2 < 8; ++h2) {
        const float Uv = UF[0][h2][tid] * FG[0][h2] + UF[1][h2][tid] * FG[1][h2]
                       + UF[2][h2][tid] * FG[2][h2] + UF[3][h2][tid] * FG[3][h2];
        u_norm[(size_t)g * 2048 + h2 * 256 + tid] = (Uv - SG[h2]) * IZ[h2] * lwj + lbj;
    }
}

// ---------------- Kernel C: g = Wv . u_norm (head-selected), out = Wout.g + 0.2*Wres.mean ----------------
// one graph per block (1024 blocks -> 4 blocks/CU, 16 waves/CU; weights are L2-resident)
__global__ __launch_bounds__(256) void k_out(
    const float* __restrict__ u_norm, const float* __restrict__ mean_raw,
    const float* __restrict__ Wv, const float* __restrict__ Wout,
    const float* __restrict__ Wres, float* __restrict__ out)
{
    const int d = threadIdx.x;
    const int g = blockIdx.x;
    __shared__ __align__(16) float UN[8][256];  // 8 KB
    __shared__ __align__(16) float MR[256];
    __shared__ __align__(16) float GF[256];

    const float4* up = (const float4*)(u_norm + (size_t)g * 2048);
    ((float4*)UN)[d] = up[d];
    ((float4*)UN)[256 + d] = up[256 + d];
    if (d < 64) ((float4*)MR)[d] = ((const float4*)(mean_raw + (size_t)g * 256))[d];
    __syncthreads();

    const int hh = d >> 5;
    float acc = 0.f;
    const float* wvr = Wv + (size_t)d * 256;
    #pragma unroll 8
    for (int j = 0; j < 256; j += 4) {
        const float4 wv = *(const float4*)(wvr + j);
        const float4 uv = *(const float4*)(&UN[hh][j]);
        acc += wv.x * uv.x + wv.y * uv.y + wv.z * uv.z + wv.w * uv.w;
    }
    GF[d] = acc;
    __syncthreads();

    float oo = 0.f, rr = 0.f;
    const float* wor = Wout + (size_t)d * 256;
    const float* wrr = Wres + (size_t)d * 256;
    #pragma unroll 8
    for (int j = 0; j < 256; j += 4) {
        const float4 wo = *(const float4*)(wor + j);
        const float4 wq = *(const float4*)(wrr + j);
        const float4 gf = *(const float4*)(&GF[j]);
        const float4 mr = *(const float4*)(&MR[j]);
        oo += wo.x * gf.x + wo.y * gf.y + wo.z * gf.z + wo.w * gf.w;
        rr += wq.x * mr.x + wq.y * mr.y + wq.z * mr.z + wq.w * mr.w;
    }
    out[(size_t)g * 256 + d] = oo + 0.2f * rr;
}

// ---------------- launch ----------------
extern "C" void kernel_launch(void* const* d_in, const int* in_sizes, int n_in,
                              void* d_out, int out_size, void* d_ws, size_t ws_size,
                              hipStream_t stream)
{
    const float* h        = (const float*)d_in[0];
    const int*   batch    = (const int*)d_in[1];
    const int*   cdr      = (const int*)d_in[2];   // bool mask arrives as int32
    const int*   ifm      = (const int*)d_in[3];   // bool mask arrives as int32
    const float* ln_kv_w  = (const float*)d_in[4];
    const float* ln_kv_b  = (const float*)d_in[5];
    const float* ln_q_w   = (const float*)d_in[6];
    const float* ln_q_b   = (const float*)d_in[7];
    const float* Wk       = (const float*)d_in[8];
    const float* Wv       = (const float*)d_in[9];
    const float* Wq       = (const float*)d_in[10];
    const float* Wres     = (const float*)d_in[11];
    const float* Wout     = (const float*)d_in[12];
    const float* cdr_b    = (const float*)d_in[13];
    const float* if_b     = (const float*)d_in[14];
    const float* lsc      = (const float*)d_in[15];

    const int N = in_sizes[0] / 256;   // 262144
    const int B = out_size / 256;      // 1024

    int*   start    = (int*)d_ws;                         // (B+1) ints
    float* mean_raw = (float*)((char*)d_ws + 8192);       // B*256 floats (1 MB)
    float* w_eff    = mean_raw + (size_t)B * 256;         // B*8*256 floats (8 MB)
    float* u_norm   = w_eff + (size_t)B * 2048;           // B*8*256 floats (8 MB)

    k_offsets<<<(N + 255) / 256, 256, 0, stream>>>(batch, start, N, B);
    k_pool_q<<<B, 256, 0, stream>>>(h, start, Wq, Wk, ln_q_w, ln_q_b, ln_kv_w, lsc,
                                    mean_raw, w_eff);
    k_attn<<<B, 256, 0, stream>>>(h, start, cdr, ifm, ln_kv_w, ln_kv_b, w_eff,
                                  cdr_b, if_b, u_norm);
    k_out<<<B, 256, 0, stream>>>(u_norm, mean_raw, Wv, Wout, Wres, (float*)d_out);
}

// Round 3
// 669.609 us; speedup vs baseline: 1.4185x; 1.4185x over previous
//
#include <hip/hip_runtime.h>

// ---------------- Kernel 0: segment offsets from sorted batch ----------------
__global__ void k_offsets(const int* __restrict__ batch, int* __restrict__ start,
                          int N, int B) {
    int i = blockIdx.x * blockDim.x + threadIdx.x;
    if (i >= N) return;
    int b = batch[i];
    if (i == 0) {
        for (int g = 0; g <= b; ++g) start[g] = 0;
    } else {
        int pb = batch[i - 1];
        for (int g = pb + 1; g <= b; ++g) start[g] = i;
    }
    if (i == N - 1) {
        for (int g = b + 1; g <= B; ++g) start[g] = N;
    }
}

// ---------------- Kernel A: pool (mean/max) -> q -> LN -> folded w_eff ----------------
// one block per graph, 256 threads.
// Pooling: wave w owns rows n = s+w, s+w+4, ...; lane l reads dims 4l..4l+3 as float4.
// w_eff is stored FOLDED: w_eff[g,h,j] = (sum_r Wk[h*32+r,j]*QL[h*32+r]) * scale * ln_kv_w[j]
// so k_attn can compute logits on RAW x:
//   logit = rstd*(dot(A,x) - mu*sum(A)) + const(g,h) + mask_bias
// and const(g,h) = sum_j we*lnb is softmax-invariant within a segment -> dropped.
__global__ __launch_bounds__(256) void k_pool_q(
    const float* __restrict__ h, const int* __restrict__ start,
    const float* __restrict__ Wq, const float* __restrict__ Wk,
    const float* __restrict__ ln_q_w, const float* __restrict__ ln_q_b,
    const float* __restrict__ ln_kv_w, const float* __restrict__ logit_scale,
    float* __restrict__ mean_raw, float* __restrict__ w_eff)
{
    const int g = blockIdx.x;
    const int tid = threadIdx.x;
    const int w = tid >> 6;
    const int l = tid & 63;
    const int d = tid;
    const int s = start[g], e = start[g + 1];

    // ---- vectorized pooling: wave-per-row, float4 per lane, 2-deep unroll ----
    float4 sm = make_float4(0.f, 0.f, 0.f, 0.f);
    float4 mx = make_float4(-INFINITY, -INFINITY, -INFINITY, -INFINITY);
    int n = s + w;
    for (; n + 4 < e; n += 8) {
        const float4 a = *(const float4*)(h + (size_t)n * 256 + l * 4);
        const float4 b = *(const float4*)(h + (size_t)(n + 4) * 256 + l * 4);
        sm.x += a.x + b.x; sm.y += a.y + b.y; sm.z += a.z + b.z; sm.w += a.w + b.w;
        mx.x = fmaxf(mx.x, fmaxf(a.x, b.x)); mx.y = fmaxf(mx.y, fmaxf(a.y, b.y));
        mx.z = fmaxf(mx.z, fmaxf(a.z, b.z)); mx.w = fmaxf(mx.w, fmaxf(a.w, b.w));
    }
    if (n < e) {
        const float4 a = *(const float4*)(h + (size_t)n * 256 + l * 4);
        sm.x += a.x; sm.y += a.y; sm.z += a.z; sm.w += a.w;
        mx.x = fmaxf(mx.x, a.x); mx.y = fmaxf(mx.y, a.y);
        mx.z = fmaxf(mx.z, a.z); mx.w = fmaxf(mx.w, a.w);
    }

    __shared__ __align__(16) float PS[4][256];
    __shared__ __align__(16) float PM[4][256];
    *(float4*)(&PS[w][l * 4]) = sm;
    *(float4*)(&PM[w][l * 4]) = mx;
    __syncthreads();
    const float sum = (PS[0][d] + PS[1][d]) + (PS[2][d] + PS[3][d]);
    const float mxv = fmaxf(fmaxf(PM[0][d], PM[1][d]), fmaxf(PM[2][d], PM[3][d]));
    const float mean = sum / (float)(e - s);
    mean_raw[(size_t)g * 256 + d] = mean;

    __shared__ __align__(16) float X[512];   // [mean | max]
    __shared__ float QL[256];
    __shared__ float rs[4], rq[4];
    X[d] = mean;
    X[256 + d] = mxv;
    __syncthreads();

    // q[d] = sum_j X[j] * Wq[d,j]   (Wq is (256,512) row-major)
    float q = 0.f;
    const float* wqr = Wq + (size_t)d * 512;
    #pragma unroll 8
    for (int j = 0; j < 512; j += 4) {
        float4 w4 = *(const float4*)(wqr + j);
        q += w4.x * X[j] + w4.y * X[j + 1] + w4.z * X[j + 2] + w4.w * X[j + 3];
    }
    // block LayerNorm over the 256 q values
    float s1 = q, s2 = q * q;
    #pragma unroll
    for (int off = 1; off < 64; off <<= 1) {
        s1 += __shfl_xor(s1, off);
        s2 += __shfl_xor(s2, off);
    }
    if ((d & 63) == 0) { rs[d >> 6] = s1; rq[d >> 6] = s2; }
    __syncthreads();
    const float t1 = rs[0] + rs[1] + rs[2] + rs[3];
    const float t2 = rq[0] + rq[1] + rq[2] + rq[3];
    const float mu = t1 * (1.f / 256.f);
    const float var = t2 * (1.f / 256.f) - mu * mu;
    const float rstd = rsqrtf(var + 1e-5f);
    QL[d] = (q - mu) * rstd * ln_q_w[d] + ln_q_b[d];
    __syncthreads();

    // folded A[h, j=d] = (sum_{d2 in head h} Wk[d2, d] * QL[d2]) * scale * ln_kv_w[d]
    const float scale = logit_scale[0] * 0.17677669529663687f; // 1/sqrt(32)
    const float fold = scale * ln_kv_w[d];
    #pragma unroll
    for (int hh = 0; hh < 8; ++hh) {
        float a = 0.f;
        #pragma unroll 8
        for (int r = 0; r < 32; ++r) {
            a += Wk[(size_t)(hh * 32 + r) * 256 + d] * QL[hh * 32 + r];
        }
        w_eff[((size_t)g * 8 + hh) * 256 + d] = a * fold;
    }
}

// ---------------- Kernel B: logits on raw x + online segment softmax + u ----------------
// one block per graph, 4 waves; wave w handles nodes s+w, s+w+4, ...
// lane layout: hh = l>>3 (head), p = l&7 (32-wide j-chunk)
// Per node: write RAW x to LDS, read chunk, compute {s1,s2,dotA} locally, ONE 3-level
// xor(1,2,4) reduce gives full LN stats AND the per-head dot. u accumulates raw x with
// weight e*rstd; the lnw/lnb correction is applied once in the epilogue:
//   sum_n e_n * h_ln[n,j] = lnw_j*(U[j] - Sw) + lnb_j*Z,  Sw = sum e*rstd*mu, Z = sum e
// NOTE: plain __launch_bounds__(256) — a (256,4) min-waves hint capped VGPR at 64 and
// spilled u[32]/hv[32] to scratch (418 MB WRITE_SIZE, 2.3x slower). Do not re-add.
__global__ __launch_bounds__(256) void k_attn(
    const float* __restrict__ h, const int* __restrict__ start,
    const int* __restrict__ cdr, const int* __restrict__ ifm,
    const float* __restrict__ ln_w, const float* __restrict__ ln_b,
    const float* __restrict__ w_eff,
    const float* __restrict__ cdr_bias, const float* __restrict__ iface_bias,
    float* __restrict__ u_norm)
{
    const int g = blockIdx.x;
    const int tid = threadIdx.x;
    const int w = tid >> 6;
    const int l = tid & 63;
    const int hh = l >> 3;
    const int p = l & 7;
    const int s = start[g], e = start[g + 1];
    const float cb = cdr_bias[0], ib = iface_bias[0];

    // folded key weights A for (head hh, chunk p)
    float we[32];
    {
        const float* wp = w_eff + ((size_t)g * 8 + hh) * 256 + p * 32;
        #pragma unroll
        for (int r = 0; r < 8; ++r) {
            float4 t = *(const float4*)(wp + r * 4);
            we[4 * r + 0] = t.x; we[4 * r + 1] = t.y; we[4 * r + 2] = t.z; we[4 * r + 3] = t.w;
        }
    }
    // s1h = sum_j A[hh][j]  (uniform across the 8 lanes of a head after reduce)
    float s1h = 0.f;
    #pragma unroll
    for (int r = 0; r < 32; ++r) s1h += we[r];
    s1h += __shfl_xor(s1h, 1);
    s1h += __shfl_xor(s1h, 2);
    s1h += __shfl_xor(s1h, 4);

    float m = -INFINITY, z = 0.f, sw = 0.f;
    float u[32];
    #pragma unroll
    for (int r = 0; r < 32; ++r) u[r] = 0.f;

    // padded row buffer: 32-float chunk c lives at float offset c*36
    __shared__ __align__(16) float hbuf[4][288];
    __shared__ __align__(16) float UF[4][8][264];   // padded: kills 16-way conflict on p*32 writes
    __shared__ float MW[4][8], ZW[4][8], SW[4][8], FG[4][8], IZ[8], SG[8];

    const int wofs = l * 4 + ((l >> 3) << 2); // padded offset of j = l*4
    const int rofs = p * 36;                  // padded base of chunk p

    int n = s + w;
    float4 xn = make_float4(0.f, 0.f, 0.f, 0.f);
    int cn = 0, im = 0;
    if (n < e) {                               // prefetch node 0
        xn = *(const float4*)(h + (size_t)n * 256 + l * 4);
        cn = cdr[n]; im = ifm[n];
    }
    while (n < e) {
        const float4 xc = xn;
        const int cc = cn, ic = im;
        const int n2 = n + 4;
        if (n2 < e) {                          // software-pipeline next node's x + masks
            xn = *(const float4*)(h + (size_t)n2 * 256 + l * 4);
            cn = cdr[n2]; im = ifm[n2];
        }

        *(float4*)(&hbuf[w][wofs]) = xc;       // RAW x (no LN yet)
        asm volatile("s_waitcnt lgkmcnt(0)" ::: "memory");

        float hv[32];
        #pragma unroll
        for (int r = 0; r < 8; ++r) {
            float4 t = *(const float4*)(&hbuf[w][rofs + r * 4]);
            hv[4 * r + 0] = t.x; hv[4 * r + 1] = t.y; hv[4 * r + 2] = t.z; hv[4 * r + 3] = t.w;
        }
        // local stats + dot over the chunk, then ONE shared 3-level reduce
        float s1 = 0.f, s2 = 0.f, dt = 0.f;
        #pragma unroll
        for (int r = 0; r < 32; ++r) {
            const float v = hv[r];
            s1 += v;
            s2 = fmaf(v, v, s2);
            dt = fmaf(v, we[r], dt);
        }
        #pragma unroll
        for (int off = 1; off < 8; off <<= 1) {
            s1 += __shfl_xor(s1, off);
            s2 += __shfl_xor(s2, off);
            dt += __shfl_xor(dt, off);
        }
        const float mu = s1 * (1.f / 256.f);
        const float var = s2 * (1.f / 256.f) - mu * mu;
        const float rstd = rsqrtf(var + 1e-5f);
        const float mb = cb * (float)cc + ib * (float)ic;
        const float lv = rstd * (dt - mu * s1h) + mb;

        const float nm = fmaxf(m, lv);
        const float ee = __expf(lv - nm);
        const float c = ee * rstd;
        if (__any(lv > m)) {                   // some head's max moved: rescale path
            const float a = __expf(m - nm);    // exp(-inf)=0 on first node
            z = z * a + ee;
            sw = sw * a + c * mu;
            #pragma unroll
            for (int r = 0; r < 32; ++r) u[r] = u[r] * a + c * hv[r];
            m = nm;
        } else {                               // common path: no rescale, 1 FMA per elem
            z += ee;
            sw += c * mu;
            #pragma unroll
            for (int r = 0; r < 32; ++r) u[r] = fmaf(c, hv[r], u[r]);
        }
        n = n2;
    }

    if (p == 0) { MW[w][hh] = m; ZW[w][hh] = z; SW[w][hh] = sw; }
    #pragma unroll
    for (int r = 0; r < 8; ++r) {
        float4 t = make_float4(u[4 * r], u[4 * r + 1], u[4 * r + 2], u[4 * r + 3]);
        *(float4*)(&UF[w][hh][p * 32 + r * 4]) = t;
    }
    __syncthreads();

    if (tid < 8) {
        const float mg = fmaxf(fmaxf(MW[0][tid], MW[1][tid]),
                               fmaxf(MW[2][tid], MW[3][tid]));
        float zg = 0.f, sg = 0.f;
        #pragma unroll
        for (int ww = 0; ww < 4; ++ww) {
            const float f = __expf(MW[ww][tid] - mg);  // empty wave: exp(-inf)=0
            FG[ww][tid] = f;
            zg += ZW[ww][tid] * f;
            sg += SW[ww][tid] * f;
        }
        IZ[tid] = 1.f / zg;
        SG[tid] = sg;
    }
    __syncthreads();

    const float lwj = ln_w[tid], lbj = ln_b[tid];
    #pragma unroll
    for (int h2 = 0; h2 < 8; ++h2) {
        const float Uv = UF[0][h2][tid] * FG[0][h2] + UF[1][h2][tid] * FG[1][h2]
                       + UF[2][h2][tid] * FG[2][h2] + UF[3][h2][tid] * FG[3][h2];
        u_norm[(size_t)g * 2048 + h2 * 256 + tid] = (Uv - SG[h2]) * IZ[h2] * lwj + lbj;
    }
}

// ---------------- Kernel C: g = Wv . u_norm (head-selected), out = Wout.g + 0.2*Wres.mean ----------------
// one graph per block (1024 blocks -> 4 blocks/CU, 16 waves/CU; weights are L2-resident)
__global__ __launch_bounds__(256) void k_out(
    const float* __restrict__ u_norm, const float* __restrict__ mean_raw,
    const float* __restrict__ Wv, const float* __restrict__ Wout,
    const float* __restrict__ Wres, float* __restrict__ out)
{
    const int d = threadIdx.x;
    const int g = blockIdx.x;
    __shared__ __align__(16) float UN[8][256];  // 8 KB
    __shared__ __align__(16) float MR[256];
    __shared__ __align__(16) float GF[256];

    const float4* up = (const float4*)(u_norm + (size_t)g * 2048);
    ((float4*)UN)[d] = up[d];
    ((float4*)UN)[256 + d] = up[256 + d];
    if (d < 64) ((float4*)MR)[d] = ((const float4*)(mean_raw + (size_t)g * 256))[d];
    __syncthreads();

    const int hh = d >> 5;
    float acc = 0.f;
    const float* wvr = Wv + (size_t)d * 256;
    #pragma unroll 8
    for (int j = 0; j < 256; j += 4) {
        const float4 wv = *(const float4*)(wvr + j);
        const float4 uv = *(const float4*)(&UN[hh][j]);
        acc += wv.x * uv.x + wv.y * uv.y + wv.z * uv.z + wv.w * uv.w;
    }
    GF[d] = acc;
    __syncthreads();

    float oo = 0.f, rr = 0.f;
    const float* wor = Wout + (size_t)d * 256;
    const float* wrr = Wres + (size_t)d * 256;
    #pragma unroll 8
    for (int j = 0; j < 256; j += 4) {
        const float4 wo = *(const float4*)(wor + j);
        const float4 wq = *(const float4*)(wrr + j);
        const float4 gf = *(const float4*)(&GF[j]);
        const float4 mr = *(const float4*)(&MR[j]);
        oo += wo.x * gf.x + wo.y * gf.y + wo.z * gf.z + wo.w * gf.w;
        rr += wq.x * mr.x + wq.y * mr.y + wq.z * mr.z + wq.w * mr.w;
    }
    out[(size_t)g * 256 + d] = oo + 0.2f * rr;
}

// ---------------- launch ----------------
extern "C" void kernel_launch(void* const* d_in, const int* in_sizes, int n_in,
                              void* d_out, int out_size, void* d_ws, size_t ws_size,
                              hipStream_t stream)
{
    const float* h        = (const float*)d_in[0];
    const int*   batch    = (const int*)d_in[1];
    const int*   cdr      = (const int*)d_in[2];   // bool mask arrives as int32
    const int*   ifm      = (const int*)d_in[3];   // bool mask arrives as int32
    const float* ln_kv_w  = (const float*)d_in[4];
    const float* ln_kv_b  = (const float*)d_in[5];
    const float* ln_q_w   = (const float*)d_in[6];
    const float* ln_q_b   = (const float*)d_in[7];
    const float* Wk       = (const float*)d_in[8];
    const float* Wv       = (const float*)d_in[9];
    const float* Wq       = (const float*)d_in[10];
    const float* Wres     = (const float*)d_in[11];
    const float* Wout     = (const float*)d_in[12];
    const float* cdr_b    = (const float*)d_in[13];
    const float* if_b     = (const float*)d_in[14];
    const float* lsc      = (const float*)d_in[15];

    const int N = in_sizes[0] / 256;   // 262144
    const int B = out_size / 256;      // 1024

    int*   start    = (int*)d_ws;                         // (B+1) ints
    float* mean_raw = (float*)((char*)d_ws + 8192);       // B*256 floats (1 MB)
    float* w_eff    = mean_raw + (size_t)B * 256;         // B*8*256 floats (8 MB)
    float* u_norm   = w_eff + (size_t)B * 2048;           // B*8*256 floats (8 MB)

    k_offsets<<<(N + 255) / 256, 256, 0, stream>>>(batch, start, N, B);
    k_pool_q<<<B, 256, 0, stream>>>(h, start, Wq, Wk, ln_q_w, ln_q_b, ln_kv_w, lsc,
                                    mean_raw, w_eff);
    k_attn<<<B, 256, 0, stream>>>(h, start, cdr, ifm, ln_kv_w, ln_kv_b, w_eff,
                                  cdr_b, if_b, u_norm);
    k_out<<<B, 256, 0, stream>>>(u_norm, mean_raw, Wv, Wout, Wres, (float*)d_out);
}